// Round 12
// baseline (2541.141 us; speedup 1.0000x reference)
//
#include <hip/hip_runtime.h>
#include <math.h>

#define BB 8
#define NN 8192
#define SS 2048
#define KK 32
#define NP (BB*SS*KK)   /* 524288 points through the MLP */
#define EPSF 1e-5f
#define TT 256          /* fps threads per block (R6: W=1 wave/SIMD optimal) */

// ---------------------------------------------------------------------------
// DPP-based wave64 max of a u64 key (dist_bits<<32 | ~p). Pure VALU.
// ---------------------------------------------------------------------------
template <int CTRL>
__device__ __forceinline__ unsigned long long dpp_max_step(unsigned long long key) {
    unsigned lo = (unsigned)key, hi = (unsigned)(key >> 32);
    unsigned nlo = (unsigned)__builtin_amdgcn_update_dpp((int)lo, (int)lo, CTRL, 0xf, 0xf, false);
    unsigned nhi = (unsigned)__builtin_amdgcn_update_dpp((int)hi, (int)hi, CTRL, 0xf, 0xf, false);
    unsigned long long nk = ((unsigned long long)nhi << 32) | nlo;
    return nk > key ? nk : key;
}

__device__ __forceinline__ unsigned long long wave_max_u64(unsigned long long key) {
    key = dpp_max_step<0x111>(key);  // row_shr:1
    key = dpp_max_step<0x112>(key);  // row_shr:2
    key = dpp_max_step<0x114>(key);  // row_shr:4
    key = dpp_max_step<0x118>(key);  // row_shr:8
    key = dpp_max_step<0x142>(key);  // row_bcast:15
    key = dpp_max_step<0x143>(key);  // row_bcast:31
    return key;                      // valid in lane 63
}

// ---------------------------------------------------------------------------
// FPS (eager, R10 structure, NO in-loop global stores): one block per batch
// (R4: cross-WG exchange ~2.5us/iter -> single-CU per batch structural).
// 256 threads = 1 wave/SIMD. 32 points/thread scalar registers.
// R11 change: the per-iteration global store of the centroid forced an
// s_waitcnt vmcnt(0) before each s_barrier (global writeback on the critical
// path, unhidden at W=1). Instead, thread (it&255) records the winner index
// into a 4KB LDS u16 history (ds_write_b16, LDS-latency only); an epilogue
// writes all 2048 centroids from the lxyz copy (exact coords -> bit-exact).
// Update = 10 VALU/pt; 4 split max accumulators; deferred argmax resolve
// scans high->low (smallest slot among ties == np.argmax). u64 key
// (dist<<32 | ~p) -> DPP wave max -> parity LDS slots -> 4-key scan ->
// centroid from 128KB LDS float4 copy. Bit-exact: contract(off),
// ((dx*dx+dy*dy)+dz*dz) via __f*_rn, exact coord copies.
// Tail: fps block 0 zeroes the BN stats buffer (replaces memset).
// ---------------------------------------------------------------------------
__global__ __launch_bounds__(TT) void fps_kernel(const float* __restrict__ xyz,
                                                 float* __restrict__ out_newxyz,
                                                 float* __restrict__ stats) {
#pragma clang fp contract(off)
    const int PPT = NN / TT;         // 32 points per thread
    int b = blockIdx.x;
    int t = threadIdx.x;
    int wid  = t >> 6;               // 0..3
    int lane = t & 63;
    const float* x = xyz + b * NN * 3;
    float* nout = out_newxyz + b * SS * 3;

    __shared__ float4 lxyz[NN];                             // 128 KB coord copy
    __shared__ __align__(16) unsigned long long skey[2][4]; // parity wave keys
    __shared__ unsigned short gihist[SS + 1];               // 4 KB winner history

    float px[PPT], py[PPT], pz[PPT], dist[PPT];
#pragma unroll
    for (int j = 0; j < PPT; j++) {
        int p = t + j * TT;
        float vx = x[p * 3 + 0];
        float vy = x[p * 3 + 1];
        float vz = x[p * 3 + 2];
        px[j] = vx; py[j] = vy; pz[j] = vz;
        lxyz[p] = make_float4(vx, vy, vz, 0.f);
        dist[j] = 1e10f;
    }
    if (t == 0) gihist[0] = 0;                        // first centroid = point 0
    __syncthreads();
    float4 c0 = lxyz[0];
    float cx = c0.x, cy = c0.y, cz = c0.z;

    for (int it = 0; it < SS; it++) {
        // scalar update, 10 VALU/pt; 4 split max accumulators (dep chain /4)
        float m0 = -1.0f, m1 = -1.0f, m2 = -1.0f, m3 = -1.0f;
#pragma unroll
        for (int j = 0; j < PPT; j++) {
            float dx = __fsub_rn(px[j], cx);
            float dy = __fsub_rn(py[j], cy);
            float dz = __fsub_rn(pz[j], cz);
            float d  = __fadd_rn(__fadd_rn(__fmul_rn(dx, dx), __fmul_rn(dy, dy)),
                                 __fmul_rn(dz, dz));
            float e = fminf(dist[j], d);
            dist[j] = e;
            if ((j & 3) == 0)      m0 = fmaxf(m0, e);
            else if ((j & 3) == 1) m1 = fmaxf(m1, e);
            else if ((j & 3) == 2) m2 = fmaxf(m2, e);
            else                   m3 = fmaxf(m3, e);
        }
        float lmax = fmaxf(fmaxf(m0, m1), fmaxf(m2, m3));
        // resolve smallest slot attaining lmax (scan high->low, low overwrites)
        int li = 0;
#pragma unroll
        for (int j = PPT - 1; j >= 0; j--)
            li = (dist[j] == lmax) ? j : li;
        int p = t + (li << 8);                         // global point index
        unsigned long long key =
            ((unsigned long long)__float_as_uint(lmax) << 32) | (unsigned)(~p);
        key = wave_max_u64(key);                       // DPP, valid in lane 63
        if (lane == 63) skey[it & 1][wid] = key;
        __syncthreads();                               // LDS-only drain now
        const ulonglong2* sk = (const ulonglong2*)&skey[it & 1][0];
        ulonglong2 ab = sk[0];                         // 2x ds_read_b128
        ulonglong2 cd = sk[1];
        unsigned long long k = ab.x;
        k = (ab.y > k) ? ab.y : k;
        k = (cd.x > k) ? cd.x : k;
        k = (cd.y > k) ? cd.y : k;
        int gi = (int)(~(unsigned)k) & (NN - 1);
        if (t == (it & 255)) gihist[it + 1] = (unsigned short)gi;  // record winner
        float4 c = lxyz[gi];                           // one broadcast ds_read_b128
        cx = c.x; cy = c.y; cz = c.z;
    }
    __syncthreads();
    // epilogue: write all 2048 centroids from the LDS copy (exact coords)
#pragma unroll
    for (int j = 0; j < SS / TT; j++) {
        int it = j * TT + t;
        float4 c = lxyz[gihist[it]];
        nout[it * 3 + 0] = c.x;
        nout[it * 3 + 1] = c.y;
        nout[it * 3 + 2] = c.z;
    }
    if (b == 0) stats[t] = 0.f;                        // zero BN stats (256 floats)
}

// ---------------------------------------------------------------------------
// Ball query: one wave per query. Ordered compaction of first 32 in-radius
// indices (== reference's where->sort->truncate), pad with first index.
// ---------------------------------------------------------------------------
__global__ __launch_bounds__(256) void ballq_kernel(const float* __restrict__ xyz,
                                                    const float* __restrict__ new_xyz,
                                                    int* __restrict__ idx_out) {
    int q    = blockIdx.x * 4 + (threadIdx.x >> 6);
    int lane = threadIdx.x & 63;
    int b    = q >> 11;                        // q / SS
    const float* x = xyz + b * NN * 3;
    const float* c = new_xyz + q * 3;
    float cx = c[0], cy = c[1], cz = c[2];
    int* out = idx_out + q * KK;
    const float R2 = (float)(0.2 * 0.2);       // match reference double->f32 cast

    int count = 0;
    int first = -1;
    for (int base = 0; base < NN; base += 64) {
        int p = base + lane;
        float dx = __fsub_rn(x[p * 3 + 0], cx);
        float dy = __fsub_rn(x[p * 3 + 1], cy);
        float dz = __fsub_rn(x[p * 3 + 2], cz);
        float d  = __fadd_rn(__fadd_rn(__fmul_rn(dx, dx), __fmul_rn(dy, dy)),
                             __fmul_rn(dz, dz));
        bool in = !(d > R2);
        unsigned long long m = __ballot(in);
        if (first < 0 && m != 0ull) first = base + __ffsll((unsigned long long)m) - 1;
        int pre = __popcll(m & ((1ull << lane) - 1ull));
        int pos = count + pre;
        if (in && pos < KK) out[pos] = p;
        count += __popcll(m);
        if (count >= KK) break;                 // wave-uniform
    }
    for (int i2 = count + lane; i2 < KK; i2 += 64) out[i2] = first;
}

// ---------------------------------------------------------------------------
// MLP helpers (thread-per-point recompute chain; weights via uniform s_loads)
// ---------------------------------------------------------------------------
__device__ __forceinline__ void load_in6(const float* __restrict__ xyz,
                                         const float* __restrict__ points,
                                         const float* __restrict__ new_xyz,
                                         const int* __restrict__ idx, int p, float inx[6]) {
    int bs = p >> 5;
    int b  = bs >> 11;
    int pt = idx[p];
    const float* xb = xyz + ((long)b * NN + pt) * 3;
    const float* pb = points + ((long)b * NN + pt) * 3;
    const float* nx = new_xyz + bs * 3;
    inx[0] = xb[0] - nx[0];
    inx[1] = xb[1] - nx[1];
    inx[2] = xb[2] - nx[2];
    inx[3] = pb[0];
    inx[4] = pb[1];
    inx[5] = pb[2];
}

template <int CIN, int COUT>
__device__ __forceinline__ void linear(const float* __restrict__ w,
                                       const float* __restrict__ bias,
                                       const float* xin, float* yout) {
#pragma unroll
    for (int o = 0; o < COUT; o++) {
        float acc = bias[o];
#pragma unroll
        for (int j = 0; j < CIN; j++) acc = fmaf(w[o * CIN + j], xin[j], acc);
        yout[o] = acc;
    }
}

// compute per-channel BN scale/shift from raw sums (threads 0..C-1)
template <int C>
__device__ __forceinline__ void bn_coef(const float* __restrict__ stats,
                                        const float* __restrict__ g,
                                        const float* __restrict__ be,
                                        float* s_sc, float* s_sh) {
    int t = threadIdx.x;
    if (t < C) {
        float mean = stats[t] * (1.0f / (float)NP);
        float var  = stats[C + t] * (1.0f / (float)NP) - mean * mean;
        float rstd = 1.0f / sqrtf(var + EPSF);
        float sc = g[t] * rstd;
        s_sc[t] = sc;
        s_sh[t] = be[t] - mean * sc;
    }
    __syncthreads();
}

// block-level channel sums via LDS transpose (33.8KB), one atomic/chan/block
template <int C>
__device__ __forceinline__ void accum_stats(const float* y, float* __restrict__ gstats) {
    __shared__ float buf[256][33];
    int t = threadIdx.x;
#pragma unroll
    for (int h = 0; h < C / 32; h++) {
        __syncthreads();
#pragma unroll
        for (int c = 0; c < 32; c++) buf[t][c] = y[h * 32 + c];
        __syncthreads();
        if (t < 32) {
            float s = 0.f, sq = 0.f;
            for (int r = 0; r < 256; r++) {
                float v = buf[r][t];
                s += v;
                sq = fmaf(v, v, sq);
            }
            atomicAdd(&gstats[h * 32 + t], s);
            atomicAdd(&gstats[C + h * 32 + t], sq);
        }
    }
}

__global__ __launch_bounds__(256) void l0_stats_kernel(
    const float* __restrict__ xyz, const float* __restrict__ points,
    const float* __restrict__ new_xyz, const int* __restrict__ idx,
    const float* __restrict__ w0, const float* __restrict__ b0_,
    float* __restrict__ stats0) {
    int p = blockIdx.x * 256 + threadIdx.x;
    float inx[6];
    load_in6(xyz, points, new_xyz, idx, p, inx);
    float y0[32];
    linear<6, 32>(w0, b0_, inx, y0);
    accum_stats<32>(y0, stats0);
}

__global__ __launch_bounds__(256) void l1_stats_kernel(
    const float* __restrict__ xyz, const float* __restrict__ points,
    const float* __restrict__ new_xyz, const int* __restrict__ idx,
    const float* __restrict__ w0, const float* __restrict__ b0_,
    const float* __restrict__ g0, const float* __restrict__ be0,
    const float* __restrict__ w1, const float* __restrict__ b1_,
    const float* __restrict__ stats0, float* __restrict__ stats1) {
    __shared__ float sc0[32], sh0[32];
    bn_coef<32>(stats0, g0, be0, sc0, sh0);
    int p = blockIdx.x * 256 + threadIdx.x;
    float inx[6];
    load_in6(xyz, points, new_xyz, idx, p, inx);
    float y0[32];
    linear<6, 32>(w0, b0_, inx, y0);
#pragma unroll
    for (int c = 0; c < 32; c++) y0[c] = fmaxf(fmaf(y0[c], sc0[c], sh0[c]), 0.f);
    float y1[32];
    linear<32, 32>(w1, b1_, y0, y1);
    accum_stats<32>(y1, stats1);
}

__global__ __launch_bounds__(256) void l2_stats_kernel(
    const float* __restrict__ xyz, const float* __restrict__ points,
    const float* __restrict__ new_xyz, const int* __restrict__ idx,
    const float* __restrict__ w0, const float* __restrict__ b0_,
    const float* __restrict__ g0, const float* __restrict__ be0,
    const float* __restrict__ w1, const float* __restrict__ b1_,
    const float* __restrict__ g1, const float* __restrict__ be1,
    const float* __restrict__ w2, const float* __restrict__ b2_,
    const float* __restrict__ stats0, const float* __restrict__ stats1,
    float* __restrict__ stats2) {
    __shared__ float sc0[32], sh0[32], sc1[32], sh1[32];
    bn_coef<32>(stats0, g0, be0, sc0, sh0);
    bn_coef<32>(stats1, g1, be1, sc1, sh1);
    int p = blockIdx.x * 256 + threadIdx.x;
    float inx[6];
    load_in6(xyz, points, new_xyz, idx, p, inx);
    float y0[32];
    linear<6, 32>(w0, b0_, inx, y0);
#pragma unroll
    for (int c = 0; c < 32; c++) y0[c] = fmaxf(fmaf(y0[c], sc0[c], sh0[c]), 0.f);
    float y1[32];
    linear<32, 32>(w1, b1_, y0, y1);
#pragma unroll
    for (int c = 0; c < 32; c++) y1[c] = fmaxf(fmaf(y1[c], sc1[c], sh1[c]), 0.f);
    float y2[64];
    linear<32, 64>(w2, b2_, y1, y2);
    accum_stats<64>(y2, stats2);
}

__global__ __launch_bounds__(256) void final_kernel(
    const float* __restrict__ xyz, const float* __restrict__ points,
    const float* __restrict__ new_xyz, const int* __restrict__ idx,
    const float* __restrict__ w0, const float* __restrict__ b0_,
    const float* __restrict__ g0, const float* __restrict__ be0,
    const float* __restrict__ w1, const float* __restrict__ b1_,
    const float* __restrict__ g1, const float* __restrict__ be1,
    const float* __restrict__ w2, const float* __restrict__ b2_,
    const float* __restrict__ g2, const float* __restrict__ be2,
    const float* __restrict__ stats0, const float* __restrict__ stats1,
    const float* __restrict__ stats2, float* __restrict__ out_points) {
    __shared__ float sc0[32], sh0[32], sc1[32], sh1[32], sc2[64], sh2[64];
    bn_coef<32>(stats0, g0, be0, sc0, sh0);
    bn_coef<32>(stats1, g1, be1, sc1, sh1);
    bn_coef<64>(stats2, g2, be2, sc2, sh2);
    int p = blockIdx.x * 256 + threadIdx.x;
    float inx[6];
    load_in6(xyz, points, new_xyz, idx, p, inx);
    float y0[32];
    linear<6, 32>(w0, b0_, inx, y0);
#pragma unroll
    for (int c = 0; c < 32; c++) y0[c] = fmaxf(fmaf(y0[c], sc0[c], sh0[c]), 0.f);
    float y1[32];
    linear<32, 32>(w1, b1_, y0, y1);
#pragma unroll
    for (int c = 0; c < 32; c++) y1[c] = fmaxf(fmaf(y1[c], sc1[c], sh1[c]), 0.f);
    float y2[64];
    linear<32, 64>(w2, b2_, y1, y2);
    // BN + relu + max over k (k == lane&31; butterfly within each 32-lane half)
#pragma unroll
    for (int c = 0; c < 64; c++) {
        float v = fmaxf(fmaf(y2[c], sc2[c], sh2[c]), 0.f);
#pragma unroll
        for (int off = 1; off < 32; off <<= 1)
            v = fmaxf(v, __shfl_xor(v, off));
        y2[c] = v;
    }
    int lane = threadIdx.x & 63;
    if ((lane & 31) == 0) {                     // k == 0 lanes write their (b,s) row
        int bs = p >> 5;
        float4* o = (float4*)(out_points + (long)bs * 64);
#pragma unroll
        for (int c4 = 0; c4 < 16; c4++)
            o[c4] = make_float4(y2[c4 * 4], y2[c4 * 4 + 1], y2[c4 * 4 + 2], y2[c4 * 4 + 3]);
    }
}

// ---------------------------------------------------------------------------
extern "C" void kernel_launch(void* const* d_in, const int* in_sizes, int n_in,
                              void* d_out, int out_size, void* d_ws, size_t ws_size,
                              hipStream_t stream) {
    (void)in_sizes; (void)n_in; (void)out_size; (void)ws_size;
    const float* xyz    = (const float*)d_in[0];
    const float* points = (const float*)d_in[1];
    const float* w0  = (const float*)d_in[2];
    const float* b0_ = (const float*)d_in[3];
    const float* g0  = (const float*)d_in[4];
    const float* be0 = (const float*)d_in[5];
    const float* w1  = (const float*)d_in[6];
    const float* b1_ = (const float*)d_in[7];
    const float* g1  = (const float*)d_in[8];
    const float* be1 = (const float*)d_in[9];
    const float* w2  = (const float*)d_in[10];
    const float* b2_ = (const float*)d_in[11];
    const float* g2  = (const float*)d_in[12];
    const float* be2 = (const float*)d_in[13];

    float* out        = (float*)d_out;
    float* out_newxyz = out;                 // (8,2048,3)
    float* out_points = out + BB * SS * 3;   // (8,2048,64)

    int*   idx    = (int*)d_ws;              // NP ints = 2MB
    float* stats  = (float*)d_ws + NP;
    float* stats0 = stats;                   // 64 floats (sum32+sq32)
    float* stats1 = stats + 64;              // 64 floats
    float* stats2 = stats + 128;             // 128 floats (sum64+sq64)

    // stats zeroing folded into fps_kernel (block 0 writes 256 zeros at end)
    fps_kernel<<<BB, TT, 0, stream>>>(xyz, out_newxyz, stats);
    ballq_kernel<<<BB * SS / 4, 256, 0, stream>>>(xyz, out_newxyz, idx);
    l0_stats_kernel<<<NP / 256, 256, 0, stream>>>(xyz, points, out_newxyz, idx, w0, b0_, stats0);
    l1_stats_kernel<<<NP / 256, 256, 0, stream>>>(xyz, points, out_newxyz, idx,
                                                  w0, b0_, g0, be0, w1, b1_, stats0, stats1);
    l2_stats_kernel<<<NP / 256, 256, 0, stream>>>(xyz, points, out_newxyz, idx,
                                                  w0, b0_, g0, be0, w1, b1_, g1, be1,
                                                  w2, b2_, stats0, stats1, stats2);
    final_kernel<<<NP / 256, 256, 0, stream>>>(xyz, points, out_newxyz, idx,
                                               w0, b0_, g0, be0, w1, b1_, g1, be1,
                                               w2, b2_, g2, be2, stats0, stats1, stats2,
                                               out_points);
}